// Round 4
// baseline (144.974 us; speedup 1.0000x reference)
//
#include <hip/hip_runtime.h>
#include <math.h>

// Distral per-task MLP: 32769 heads, h = relu(W1[3->100] x + b1),
// p = softmax(W2[100->5] h + b2).  ~3.6 KB read/head, ~119 MB total.
//
// R4: persistent waves + register-only software pipeline across heads.
// R2/R3 equality showed the bottleneck is the per-head phase gap: each
// one-shot wave issues ~3.6 KB, sleeps on vmcnt(0), computes, dies --
// loads are never in flight during compute.  Now 8192 persistent waves
// each stream 4-5 heads, issuing head h+1's 18-load batch BEFORE
// consuming head h's registers; the compiler's per-register waitcnt
// keeps the next batch in flight through compute+store.  No LDS at all
// (no DMA-vs-ds_read vmcnt(0) coupling).  Tail lanes use index-clamped
// full-exec loads + one cndmask instead of exec-masked loads.

#define N_HEADS 32769
#define HID     100
#define OUT     5
#define NWAVES  8192            // 2048 blocks x 4 waves

struct Batch {
    float w1a0, w1a1, w1a2;     // W1 row `lane`
    float w1b0, w1b1, w1b2;     // W1 row `lane+64` (index-clamped)
    float b1a, b1b;
    float w2a[OUT], w2b[OUT];   // W2[o][lane], W2[o][lane+64 clamped]
    float x0, x1, x2;           // wave-uniform (SGPR)
    float b2v[OUT];             // wave-uniform (SGPR)
};

static __device__ __forceinline__ Batch load_batch(
    const float* __restrict__ x,  const float* __restrict__ W1,
    const float* __restrict__ b1, const float* __restrict__ W2,
    const float* __restrict__ b2, int head, int lane)
{
    Batch t;
    const float* W1h = W1 + (size_t)head * 300;
    const float* b1h = b1 + (size_t)head * 100;
    const float* W2h = W2 + (size_t)head * 500;
    const int j2 = (lane + 64 < HID) ? (lane + 64) : (HID - 1);  // clamp, full-exec

    t.w1a0 = W1h[3 * lane + 0];
    t.w1a1 = W1h[3 * lane + 1];
    t.w1a2 = W1h[3 * lane + 2];
    t.w1b0 = W1h[3 * j2 + 0];
    t.w1b1 = W1h[3 * j2 + 1];
    t.w1b2 = W1h[3 * j2 + 2];
    t.b1a  = b1h[lane];
    t.b1b  = b1h[j2];
#pragma unroll
    for (int o = 0; o < OUT; ++o) {
        t.w2a[o] = W2h[o * HID + lane];   // 64 consecutive floats: coalesced
        t.w2b[o] = W2h[o * HID + j2];
    }
    t.x0 = x[head * 3 + 0];
    t.x1 = x[head * 3 + 1];
    t.x2 = x[head * 3 + 2];
#pragma unroll
    for (int o = 0; o < OUT; ++o) t.b2v[o] = b2[head * OUT + o];
    return t;
}

// one step of the wave64 DPP reduction: acc += dpp(acc)   (verified R3)
template <int CTRL, int ROW_MASK>
static __device__ __forceinline__ float dpp_add_step(float acc) {
    union { float f; int i; } in, out;
    in.f = acc;
    out.i = __builtin_amdgcn_update_dpp(0, in.i, CTRL, ROW_MASK, 0xF, false);
    return acc + out.f;
}

static __device__ __forceinline__ float wave_reduce_add(float acc) {
    acc = dpp_add_step<0x111, 0xF>(acc);  // row_shr:1
    acc = dpp_add_step<0x112, 0xF>(acc);  // row_shr:2
    acc = dpp_add_step<0x114, 0xF>(acc);  // row_shr:4
    acc = dpp_add_step<0x118, 0xF>(acc);  // row_shr:8
    acc = dpp_add_step<0x142, 0xA>(acc);  // row_bcast:15 -> rows 1,3
    acc = dpp_add_step<0x143, 0xC>(acc);  // row_bcast:31 -> rows 2,3
    union { float f; int i; } v, r;
    v.f = acc;
    r.i = __builtin_amdgcn_readlane(v.i, 63);  // wave-uniform total
    return r.f;
}

static __device__ __forceinline__ void process(
    const Batch& t, int head, int lane, float* __restrict__ out)
{
    const bool has2 = (lane < HID - 64);   // lanes 0..35 own h[lane+64]

    float h0 = fmaxf(fmaf(t.w1a0, t.x0, fmaf(t.w1a1, t.x1,
                     fmaf(t.w1a2, t.x2, t.b1a))), 0.0f);
    float h1 = fmaxf(fmaf(t.w1b0, t.x0, fmaf(t.w1b1, t.x1,
                     fmaf(t.w1b2, t.x2, t.b1b))), 0.0f);
    h1 = has2 ? h1 : 0.0f;                 // zero clamped-duplicate lanes

    float logit[OUT];
#pragma unroll
    for (int o = 0; o < OUT; ++o) {
        float p = fmaf(t.w2b[o], h1, t.w2a[o] * h0);
        logit[o] = wave_reduce_add(p) + t.b2v[o];
    }

    float m = -INFINITY;
#pragma unroll
    for (int o = 0; o < OUT; ++o) m = fmaxf(m, logit[o]);
    float e[OUT], s = 0.0f;
#pragma unroll
    for (int o = 0; o < OUT; ++o) { e[o] = __expf(logit[o] - m); s += e[o]; }
    const float inv = 1.0f / s;

    if (lane < OUT) {
        float v = (lane == 0) ? e[0]
                : (lane == 1) ? e[1]
                : (lane == 2) ? e[2]
                : (lane == 3) ? e[3]
                :               e[4];
        out[(size_t)head * OUT + lane] = v * inv;
    }
}

__global__ __launch_bounds__(256) void distral_kernel(
    const float* __restrict__ x,
    const float* __restrict__ W1,
    const float* __restrict__ b1,
    const float* __restrict__ W2,
    const float* __restrict__ b2,
    float* __restrict__ out)
{
    const int lane = threadIdx.x & 63;
    const int w    = (blockIdx.x << 2) | (threadIdx.x >> 6);   // 0..NWAVES-1

    int head  = w;                                   // w < NWAVES <= N_HEADS
    Batch cur = load_batch(x, W1, b1, W2, b2, head, lane);

    for (;;) {
        const int next  = head + NWAVES;             // strided: locality window
        const bool more = (next < N_HEADS);          // wave-uniform
        Batch nxt;
        if (more)
            nxt = load_batch(x, W1, b1, W2, b2, next, lane);  // issue BEFORE consume

        process(cur, head, lane, out);

        if (!more) break;
        cur  = nxt;
        head = next;
    }
}

extern "C" void kernel_launch(void* const* d_in, const int* in_sizes, int n_in,
                              void* d_out, int out_size, void* d_ws, size_t ws_size,
                              hipStream_t stream) {
    const float* x  = (const float*)d_in[0];
    const float* W1 = (const float*)d_in[1];
    const float* b1 = (const float*)d_in[2];
    const float* W2 = (const float*)d_in[3];
    const float* b2 = (const float*)d_in[4];
    float* out = (float*)d_out;

    distral_kernel<<<NWAVES / 4, 256, 0, stream>>>(x, W1, b1, W2, b2, out);
}